// Round 1
// baseline (1304.672 us; speedup 1.0000x reference)
//
#include <hip/hip_runtime.h>
#include <cstdint>
#include <cstddef>

// ---------------------------------------------------------------------------
// RNN_Decoder: B=64, T=50, E=H=512, V=30000, fp32 in/out, bf16 MFMA compute.
// Pipeline: prep (bf16 casts + embed gather) -> G0 = X@W_ih^T + biases (MFMA)
//           -> 50x LSTM step (tiny MFMA, direct global frag loads)
//           -> out = Hs@W_fc^T + b_fc (MFMA, permuted store [t,b]->[b,t]).
// ---------------------------------------------------------------------------

typedef short bf16x8 __attribute__((ext_vector_type(8)));   // 8 bf16 = 4 VGPRs
typedef float f32x4 __attribute__((ext_vector_type(4)));

#define B_    64
#define T_    50
#define E_    512
#define H_    512
#define V_    30000
#define VPAD  30080      // 235 * 128, padded rows of W_fc are zero
#define TB_   3200       // T_*B_

__device__ __forceinline__ unsigned short f2bf(float f) {
  // round-to-nearest-even f32 -> bf16 (inputs are finite; no NaN path needed)
  unsigned int u = __float_as_uint(f);
  u += 0x7fffu + ((u >> 16) & 1u);
  return (unsigned short)(u >> 16);
}

__device__ __forceinline__ void async_copy16(const void* g, void* l) {
  // global -> LDS direct copy, 16B per lane. LDS dest must be
  // wave-uniform-base + lane*16 (guide §5 caveat) — all call sites satisfy it.
  __builtin_amdgcn_global_load_lds(
      (__attribute__((address_space(1))) void*)g,
      (__attribute__((address_space(3))) void*)l, 16, 0, 0);
}

// ---------------------------- prep kernels ---------------------------------

__global__ __launch_bounds__(256) void convert_bf16_kernel(
    const float* __restrict__ src, unsigned short* __restrict__ dst, int n) {
  int i = blockIdx.x * 256 + threadIdx.x;
  if (i < n) dst[i] = f2bf(src[i]);
}

__global__ __launch_bounds__(256) void convert_pad_wfc_kernel(
    const float* __restrict__ src, unsigned short* __restrict__ dst) {
  int i = blockIdx.x * 256 + threadIdx.x;  // over VPAD*512
  if (i >= VPAD * 512) return;
  int row = i >> 9;
  dst[i] = (row < V_) ? f2bf(src[i]) : (unsigned short)0;
}

__global__ __launch_bounds__(256) void build_x_kernel(
    const float* __restrict__ x, const int* __restrict__ caption,
    const float* __restrict__ emb, unsigned short* __restrict__ X) {
  int i = blockIdx.x * 256 + threadIdx.x;  // over TB_*512
  if (i >= TB_ * 512) return;
  int r = i >> 9, e = i & 511;
  int t = r >> 6, b = r & 63;
  float v = (t == 0) ? x[b * 512 + e]
                     : emb[(size_t)caption[b * T_ + t] * 512 + e];
  X[i] = f2bf(v);
}

__global__ __launch_bounds__(256) void zero_state_kernel(
    unsigned short* __restrict__ h0, unsigned short* __restrict__ h1,
    float* __restrict__ c) {
  int i = blockIdx.x * 256 + threadIdx.x;
  if (i < B_ * H_) { h0[i] = 0; h1[i] = 0; c[i] = 0.f; }
}

// ------------------- GEMM: G0 = X @ W_ih^T + b_ih + b_hh -------------------
// m97 structure: 128x128 tile, BK=32, 4 waves (2x2 of 64x64), 16x16x32 MFMA.

__global__ __launch_bounds__(256) void gemm_g0_kernel(
    const unsigned short* __restrict__ A,    // X_bf [3200][512]
    const unsigned short* __restrict__ Bm,   // Wih_bf [2048][512] (n-major)
    const float* __restrict__ b_ih, const float* __restrict__ b_hh,
    float* __restrict__ G0) {                // [3200][2048]
  __shared__ __align__(16) unsigned short As[128 * 32];
  __shared__ __align__(16) unsigned short Bs[128 * 32];
  const int tid = threadIdx.x;
  const int lane = tid & 63;
  const int w = tid >> 6;
  const int wm = (w >> 1) * 64;
  const int wn = (w & 1) * 64;
  const int m0 = blockIdx.y * 128;
  const int n0 = blockIdx.x * 128;
  const int srow = w * 16 + (lane >> 2);     // staging: lds off = w*1024 + lane*16
  const int skoff = (lane & 3) * 8;

  const f32x4 fzero = {0.f, 0.f, 0.f, 0.f};
  f32x4 acc[4][4];
#pragma unroll
  for (int i = 0; i < 4; i++)
#pragma unroll
    for (int j = 0; j < 4; j++) acc[i][j] = fzero;

  for (int k0 = 0; k0 < 512; k0 += 32) {
    async_copy16(A + (size_t)(m0 + srow) * 512 + k0 + skoff, &As[srow * 32 + skoff]);
    async_copy16(A + (size_t)(m0 + srow + 64) * 512 + k0 + skoff, &As[(srow + 64) * 32 + skoff]);
    async_copy16(Bm + (size_t)(n0 + srow) * 512 + k0 + skoff, &Bs[srow * 32 + skoff]);
    async_copy16(Bm + (size_t)(n0 + srow + 64) * 512 + k0 + skoff, &Bs[(srow + 64) * 32 + skoff]);
    __syncthreads();
    const int fr = lane & 15;
    const int fk = (lane >> 4) * 8;
    bf16x8 af[4], bfv[4];
#pragma unroll
    for (int i = 0; i < 4; i++) {
      af[i] = *(const bf16x8*)&As[(wm + i * 16 + fr) * 32 + fk];
      bfv[i] = *(const bf16x8*)&Bs[(wn + i * 16 + fr) * 32 + fk];
    }
#pragma unroll
    for (int i = 0; i < 4; i++)
#pragma unroll
      for (int j = 0; j < 4; j++)
        acc[i][j] = __builtin_amdgcn_mfma_f32_16x16x32_bf16(af[i], bfv[j], acc[i][j], 0, 0, 0);
    __syncthreads();
  }
  const int quad = lane >> 4;
  const int colj = lane & 15;
#pragma unroll
  for (int j = 0; j < 4; j++) {
    const int n = n0 + wn + j * 16 + colj;
    const float bv = b_ih[n] + b_hh[n];
#pragma unroll
    for (int i = 0; i < 4; i++) {
      const int rb = m0 + wm + i * 16 + quad * 4;
#pragma unroll
      for (int p = 0; p < 4; p++)
        G0[(size_t)(rb + p) * 2048 + n] = acc[i][j][p] + bv;
    }
  }
}

// --------------------------- LSTM step kernel ------------------------------
// grid = 32 WGs; WG j0 owns h-columns [j0, j0+16) across all 4 gates.
// gates[64, {g*512+j0..+16}] = h_in @ W_hh^T (+G0 in epilogue), K=512.
// No LDS: direct global->VGPR fragment loads (h 64KB, W_hh 2MB, cache-hot).
// Wave w computes batch rows [w*16, w*16+16) x 4 gate tiles.

__global__ __launch_bounds__(256) void lstm_step_kernel(
    const unsigned short* __restrict__ h_in,   // [64][512] bf16
    unsigned short* __restrict__ h_out,        // [64][512] bf16
    const unsigned short* __restrict__ Whh,    // [2048][512] bf16
    const float* __restrict__ G0,              // [3200][2048]
    float* __restrict__ c,                     // [64][512] fp32
    unsigned short* __restrict__ Hs,           // [3200][512] bf16
    int t) {
  const int tid = threadIdx.x;
  const int lane = tid & 63;
  const int w = tid >> 6;
  const int j0 = blockIdx.x * 16;
  const int fr = lane & 15;
  const int quad = lane >> 4;
  const int fk = quad * 8;

  const f32x4 fzero = {0.f, 0.f, 0.f, 0.f};
  f32x4 acc[4] = {fzero, fzero, fzero, fzero};

  const unsigned short* arow = h_in + (size_t)(w * 16 + fr) * 512 + fk;
#pragma unroll
  for (int ks = 0; ks < 16; ks++) {
    bf16x8 af = *(const bf16x8*)(arow + ks * 32);
#pragma unroll
    for (int g = 0; g < 4; g++) {
      bf16x8 bv = *(const bf16x8*)&Whh[(size_t)(g * 512 + j0 + fr) * 512 + ks * 32 + fk];
      acc[g] = __builtin_amdgcn_mfma_f32_16x16x32_bf16(af, bv, acc[g], 0, 0, 0);
    }
  }

  const int j = j0 + fr;          // h column this lane owns (C/D col = lane&15)
#pragma unroll
  for (int p = 0; p < 4; p++) {
    const int b = w * 16 + quad * 4 + p;   // batch row (C/D row = quad*4+reg)
    const float* g0r = G0 + (size_t)(t * 64 + b) * 2048;
    float iv = acc[0][p] + g0r[j];
    float fv = acc[1][p] + g0r[512 + j];
    float gv = acc[2][p] + g0r[1024 + j];
    float ov = acc[3][p] + g0r[1536 + j];
    iv = 1.f / (1.f + __expf(-iv));
    fv = 1.f / (1.f + __expf(-fv));
    gv = tanhf(gv);
    ov = 1.f / (1.f + __expf(-ov));
    const int ci = b * 512 + j;
    float cn = fv * c[ci] + iv * gv;
    c[ci] = cn;
    float hn = ov * tanhf(cn);
    unsigned short hb = f2bf(hn);
    h_out[ci] = hb;
    Hs[(size_t)(t * 64 + b) * 512 + j] = hb;
  }
}

// ----------------- GEMM: out[b,t,v] = Hs @ W_fc^T + b_fc -------------------

__global__ __launch_bounds__(256) void gemm_out_kernel(
    const unsigned short* __restrict__ A,    // Hs [3200][512]
    const unsigned short* __restrict__ Bm,   // Wfc_bf [30080][512] (padded)
    const float* __restrict__ bias,          // b_fc [30000]
    float* __restrict__ out) {               // [64][50][30000]
  __shared__ __align__(16) unsigned short As[128 * 32];
  __shared__ __align__(16) unsigned short Bs[128 * 32];
  const int tid = threadIdx.x;
  const int lane = tid & 63;
  const int w = tid >> 6;
  const int wm = (w >> 1) * 64;
  const int wn = (w & 1) * 64;
  const int m0 = blockIdx.y * 128;
  const int n0 = blockIdx.x * 128;
  const int srow = w * 16 + (lane >> 2);
  const int skoff = (lane & 3) * 8;

  const f32x4 fzero = {0.f, 0.f, 0.f, 0.f};
  f32x4 acc[4][4];
#pragma unroll
  for (int i = 0; i < 4; i++)
#pragma unroll
    for (int j = 0; j < 4; j++) acc[i][j] = fzero;

  for (int k0 = 0; k0 < 512; k0 += 32) {
    async_copy16(A + (size_t)(m0 + srow) * 512 + k0 + skoff, &As[srow * 32 + skoff]);
    async_copy16(A + (size_t)(m0 + srow + 64) * 512 + k0 + skoff, &As[(srow + 64) * 32 + skoff]);
    async_copy16(Bm + (size_t)(n0 + srow) * 512 + k0 + skoff, &Bs[srow * 32 + skoff]);
    async_copy16(Bm + (size_t)(n0 + srow + 64) * 512 + k0 + skoff, &Bs[(srow + 64) * 32 + skoff]);
    __syncthreads();
    const int fr = lane & 15;
    const int fk = (lane >> 4) * 8;
    bf16x8 af[4], bfv[4];
#pragma unroll
    for (int i = 0; i < 4; i++) {
      af[i] = *(const bf16x8*)&As[(wm + i * 16 + fr) * 32 + fk];
      bfv[i] = *(const bf16x8*)&Bs[(wn + i * 16 + fr) * 32 + fk];
    }
#pragma unroll
    for (int i = 0; i < 4; i++)
#pragma unroll
      for (int j = 0; j < 4; j++)
        acc[i][j] = __builtin_amdgcn_mfma_f32_16x16x32_bf16(af[i], bfv[j], acc[i][j], 0, 0, 0);
    __syncthreads();
  }
  const int quad = lane >> 4;
  const int colj = lane & 15;
#pragma unroll
  for (int j = 0; j < 4; j++) {
    const int v = n0 + wn + j * 16 + colj;
    if (v >= V_) continue;                 // only last col-tile partially valid
    const float bv = bias[v];
#pragma unroll
    for (int i = 0; i < 4; i++) {
      const int rb = m0 + wm + i * 16 + quad * 4;
#pragma unroll
      for (int p = 0; p < 4; p++) {
        const int r = rb + p;              // r = t*64 + b
        const int tt = r >> 6, bb = r & 63;
        out[(size_t)(bb * T_ + tt) * V_ + v] = acc[i][j][p] + bv;
      }
    }
  }
}

// ------------------------------- launch ------------------------------------

extern "C" void kernel_launch(void* const* d_in, const int* in_sizes, int n_in,
                              void* d_out, int out_size, void* d_ws, size_t ws_size,
                              hipStream_t stream) {
  const float* x       = (const float*)d_in[0];
  const int*   caption = (const int*)d_in[1];
  const float* emb     = (const float*)d_in[2];
  const float* W_ih    = (const float*)d_in[3];
  const float* W_hh    = (const float*)d_in[4];
  const float* b_ih    = (const float*)d_in[5];
  const float* b_hh    = (const float*)d_in[6];
  const float* W_fc    = (const float*)d_in[7];
  const float* b_fc    = (const float*)d_in[8];
  float* out = (float*)d_out;

  char* p = (char*)d_ws;
  auto alloc = [&](size_t bytes) {
    char* r = p;
    p += (bytes + 255) & ~(size_t)255;
    return r;
  };
  unsigned short* Wih_bf = (unsigned short*)alloc((size_t)2048 * 512 * 2);
  unsigned short* Whh_bf = (unsigned short*)alloc((size_t)2048 * 512 * 2);
  unsigned short* Wfc_bf = (unsigned short*)alloc((size_t)VPAD * 512 * 2);
  unsigned short* X_bf   = (unsigned short*)alloc((size_t)TB_ * 512 * 2);
  unsigned short* Hs     = (unsigned short*)alloc((size_t)TB_ * 512 * 2);
  unsigned short* hb0    = (unsigned short*)alloc((size_t)B_ * H_ * 2);
  unsigned short* hb1    = (unsigned short*)alloc((size_t)B_ * H_ * 2);
  float* cbuf            = (float*)alloc((size_t)B_ * H_ * 4);
  float* G0              = (float*)alloc((size_t)TB_ * 2048 * 4);
  // total ws use: ~68 MB

  convert_bf16_kernel<<<(2048 * 512 + 255) / 256, 256, 0, stream>>>(W_ih, Wih_bf, 2048 * 512);
  convert_bf16_kernel<<<(2048 * 512 + 255) / 256, 256, 0, stream>>>(W_hh, Whh_bf, 2048 * 512);
  convert_pad_wfc_kernel<<<(VPAD * 512 + 255) / 256, 256, 0, stream>>>(W_fc, Wfc_bf);
  build_x_kernel<<<(TB_ * 512 + 255) / 256, 256, 0, stream>>>(x, caption, emb, X_bf);
  zero_state_kernel<<<(B_ * H_ + 255) / 256, 256, 0, stream>>>(hb0, hb1, cbuf);

  gemm_g0_kernel<<<dim3(16, 25), 256, 0, stream>>>(X_bf, Wih_bf, b_ih, b_hh, G0);

  for (int t = 0; t < T_; t++) {
    const unsigned short* hin = (t & 1) ? hb1 : hb0;
    unsigned short* hout      = (t & 1) ? hb0 : hb1;
    lstm_step_kernel<<<32, 256, 0, stream>>>(hin, hout, Whh_bf, G0, cbuf, Hs, t);
  }

  gemm_out_kernel<<<dim3(235, 25), 256, 0, stream>>>(Hs, Wfc_bf, b_fc, out);
}